// Round 8
// baseline (350.590 us; speedup 1.0000x reference)
//
#include <hip/hip_runtime.h>
#include <cstdint>
#include <cstddef>

#define B_ 16
#define E_ 1024
#define N_ 1024
#define H_ 128
#define CAP 256   // max nonzeros per row/col; Bernoulli(0.1,1024): mean 102, std 9.6
#define NC 16     // e-chunks for column build
#define EC 64     // E_/NC

typedef unsigned short u16;

#define DOT4(dst, k, q) \
    dst = fmaf((k).x, (q).x, dst); dst = fmaf((k).y, (q).y, dst); \
    dst = fmaf((k).z, (q).z, dst); dst = fmaf((k).w, (q).w, dst)
#define ACC4(a, s, k) \
    (a).x = fmaf((s), (k).x, (a).x); (a).y = fmaf((s), (k).y, (a).y); \
    (a).z = fmaf((s), (k).z, (a).z); (a).w = fmaf((s), (k).w, (a).w)

__device__ __forceinline__ float wave_sum64(float v) {
    v += __shfl_xor(v, 32);
    v += __shfl_xor(v, 16);
    v += __shfl_xor(v, 8);
    v += __shfl_xor(v, 4);
    v += __shfl_xor(v, 2);
    v += __shfl_xor(v, 1);
    return v;
}

// Row nonzero lists: one block per (b,e). Coalesced, ordered (ascending n).
__global__ void build_rows(const float* __restrict__ adj,
                           u16* __restrict__ idx, int* __restrict__ cnt_out) {
    int be = blockIdx.x;                      // b*E + e
    const float* row = adj + (size_t)be * N_;
    __shared__ int wcnt[4];
    __shared__ int base;
    int tid = threadIdx.x, lane = tid & 63, wv = tid >> 6;
    if (tid == 0) base = 0;
    __syncthreads();
    for (int c0 = 0; c0 < N_; c0 += 256) {
        float v = row[c0 + tid];
        unsigned long long m = __ballot(v != 0.0f);
        if (lane == 0) wcnt[wv] = __popcll(m);
        __syncthreads();
        int pos = base;
        for (int w = 0; w < wv; ++w) pos += wcnt[w];
        pos += __popcll(m & ((1ull << lane) - 1ull));
        if (v != 0.0f && pos < CAP)
            idx[(size_t)be * CAP + pos] = (u16)(c0 + tid);
        __syncthreads();
        if (tid == 0) base += wcnt[0] + wcnt[1] + wcnt[2] + wcnt[3];
        __syncthreads();
    }
    if (tid == 0) cnt_out[be] = base < CAP ? base : CAP;
}

// --- Column lists, 3-phase parallel, deterministic (ascending e) ---
__global__ void col_count(const float* __restrict__ adj, int* __restrict__ cnt_chunk) {
    int blk = blockIdx.x;
    int ng = blk & 3;                 // n-group
    int c  = (blk >> 2) & (NC - 1);   // e-chunk
    int b  = blk >> 6;
    int n = (ng << 8) + threadIdx.x;
    const float* base = adj + ((size_t)(b * E_ + c * EC)) * N_ + n;
    int cc = 0;
#pragma unroll 8
    for (int e = 0; e < EC; ++e)
        cc += (base[(size_t)e * N_] != 0.0f);
    cnt_chunk[(size_t)(b * NC + c) * N_ + n] = cc;
}

__global__ void col_prefix(const int* __restrict__ cnt_chunk,
                           int* __restrict__ off_chunk, int* __restrict__ cnt_out) {
    int idx = blockIdx.x * 256 + threadIdx.x;   // b*N + n
    int b = idx >> 10, n = idx & 1023;
    int run = 0;
    for (int c = 0; c < NC; ++c) {
        size_t p = (size_t)(b * NC + c) * N_ + n;
        off_chunk[p] = run;
        run += cnt_chunk[p];
    }
    cnt_out[idx] = run < CAP ? run : CAP;
}

__global__ void col_place(const float* __restrict__ adj,
                          const int* __restrict__ off_chunk, u16* __restrict__ idx) {
    int blk = blockIdx.x;
    int ng = blk & 3;
    int c  = (blk >> 2) & (NC - 1);
    int b  = blk >> 6;
    int n = (ng << 8) + threadIdx.x;
    const float* base = adj + ((size_t)(b * E_ + c * EC)) * N_ + n;
    int pos = off_chunk[(size_t)(b * NC + c) * N_ + n];
    u16* lst = idx + ((size_t)b * N_ + n) * CAP;
    for (int e = 0; e < EC; ++e) {
        if (base[(size_t)e * N_] != 0.0f) {
            if (pos < CAP) lst[pos] = (u16)(c * EC + e);
            ++pos;
        }
    }
}

// edge_init[b,e,:] = mean of incident node rows. 256 thr, float4, 8 slices.
__global__ void edge_init(const float* __restrict__ nodes,
                          const u16* __restrict__ ridx, const int* __restrict__ rcnt,
                          float* __restrict__ edge) {
    int be = blockIdx.x;
    int b = be >> 10;
    int tid = threadIdx.x, d4 = tid & 31, h = tid >> 5;
    __shared__ u16 sidx[CAP];
    __shared__ float4 part4[256];
    int cnt = rcnt[be];
    for (int i = tid; i < cnt; i += 256) sidx[i] = ridx[(size_t)be * CAP + i];
    __syncthreads();
    const float4* nb4 = (const float4*)(nodes + (size_t)b * N_ * H_);
    float4 acc = make_float4(0.f, 0.f, 0.f, 0.f);
    for (int i = h; i < cnt; i += 8) {
        float4 v = nb4[((unsigned)sidx[i] << 5) + d4];
        acc.x += v.x; acc.y += v.y; acc.z += v.z; acc.w += v.w;
    }
    part4[tid] = acc;
    __syncthreads();
    if (tid < 32) {
        float4 r = make_float4(0.f, 0.f, 0.f, 0.f);
#pragma unroll
        for (int k = 0; k < 8; ++k) {
            float4 p = part4[tid + (k << 5)];
            r.x += p.x; r.y += p.y; r.z += p.z; r.w += p.w;
        }
        float inv = 1.0f / (float)(cnt > 0 ? cnt : 1);
        r.x *= inv; r.y *= inv; r.z *= inv; r.w *= inv;
        ((float4*)edge)[(size_t)be * 32 + tid] = r;
    }
}

// Single-touch fused masked-softmax attention, 4 lanes per entry.
// Wave round = 16 entries. Per entry: 4 lanes x 32 dims (8 float4) in regs,
// dot -> TWO shfl levels -> leaky -> exp (no max shift, r5-validated) ->
// acc += ww*row in registers. ~6 wave-instr/entry vs 11 in the 8-lane form.
// Merge: sacc[j][tid] (16 B thread stride, conflict-free) -> 2-stage LDS sum.
// Denominator: each entry counted by its 4 lanes -> x0.25 at the end.
// Tail: wave-uniform break when this wave's 16-entry slice is past cnt.
// Safe for qsrc == out (block reads only its own q row, writes only its row).
// XCD swizzle: batch b on XCD b%8 -> per-XCD kv footprint 1 MB (L2-resident).
__global__ void __launch_bounds__(256, 4)
attn_gather(const float* __restrict__ qsrc,
            const float* __restrict__ kv,
            const float* __restrict__ w,
            const u16* __restrict__ lidx, const int* __restrict__ lcnt,
            float* __restrict__ out) {
    int x = blockIdx.x;
    int xcd = x & 7;
    int jb = x >> 3;                     // 0..2047
    int b = xcd + ((jb >> 10) << 3);     // batches {xcd, xcd+8}
    int rrow = jb & 1023;
    int br = (b << 10) + rrow;
    int tid = threadIdx.x, lane = tid & 63, wv = tid >> 6;   // 256 threads
    __shared__ float qsh[H_];
    __shared__ u16 sidx[CAP];
    __shared__ float4 sacc[8][256];      // [reg j][thread] merge buffer, 32 KB
    __shared__ float4 pm[4][32];
    __shared__ float dnw[4];
    int cnt = lcnt[br];
    for (int i = tid; i < cnt; i += 256) sidx[i] = lidx[(size_t)br * CAP + i];
    if (tid < H_) qsh[tid] = qsrc[(size_t)br * H_ + tid] * w[tid];
    __syncthreads();
    float wb = w[H_];
    const float4* kvb4 = (const float4*)(kv + (size_t)b * 1024 * H_);

    int esub = lane >> 2, dsub = lane & 3;   // entry-in-wave (16), d-slice (4)
    // q: 32 dims per lane as 8 float4 (same-address broadcast reads, free)
    float4 qr0 = ((const float4*)qsh)[dsub];
    float4 qr1 = ((const float4*)qsh)[4 + dsub];
    float4 qr2 = ((const float4*)qsh)[8 + dsub];
    float4 qr3 = ((const float4*)qsh)[12 + dsub];
    float4 qr4 = ((const float4*)qsh)[16 + dsub];
    float4 qr5 = ((const float4*)qsh)[20 + dsub];
    float4 qr6 = ((const float4*)qsh)[24 + dsub];
    float4 qr7 = ((const float4*)qsh)[28 + dsub];
    float4 a0 = make_float4(0.f, 0.f, 0.f, 0.f);
    float4 a1 = a0, a2 = a0, a3 = a0, a4 = a0, a5 = a0, a6 = a0, a7 = a0;
    float dpart = 0.f;
    int ibase = (esub << 2) + dsub;       // unused; keep indexing simple below
    (void)ibase;
    int went = wv << 4;                   // this wave's entry offset in a round

    for (int i0 = 0; i0 + went < cnt; i0 += 64) {
        int i = i0 + went + esub;
        unsigned ro = (unsigned)((i < cnt) ? sidx[i] : 0) << 5;
        const float4* kp = kvb4 + ro + dsub;
        float4 k0 = kp[0],  k1 = kp[4],  k2 = kp[8],  k3 = kp[12];
        float4 k4 = kp[16], k5 = kp[20], k6 = kp[24], k7 = kp[28];
        float dA = 0.f, dB = 0.f;
        DOT4(dA, k0, qr0); DOT4(dB, k1, qr1);
        DOT4(dA, k2, qr2); DOT4(dB, k3, qr3);
        DOT4(dA, k4, qr4); DOT4(dB, k5, qr5);
        DOT4(dA, k6, qr6); DOT4(dB, k7, qr7);
        float d = dA + dB;
        d += __shfl_xor(d, 1);
        d += __shfl_xor(d, 2);            // 4-lane reduce: full dot on all 4
        float p = d + wb;
        p = p >= 0.f ? p : 0.2f * p;      // LeakyReLU(0.2)
        float ww = (i < cnt) ? __expf(p) : 0.f;
        dpart += ww;
        ACC4(a0, ww, k0); ACC4(a1, ww, k1);
        ACC4(a2, ww, k2); ACC4(a3, ww, k3);
        ACC4(a4, ww, k4); ACC4(a5, ww, k5);
        ACC4(a6, ww, k6); ACC4(a7, ww, k7);
    }

    // per-wave denom (each entry counted by its 4 lanes -> x0.25 at the end)
    dpart = wave_sum64(dpart);
    if (lane == 0) dnw[wv] = dpart;
    sacc[0][tid] = a0; sacc[1][tid] = a1; sacc[2][tid] = a2; sacc[3][tid] = a3;
    sacc[4][tid] = a4; sacc[5][tid] = a5; sacc[6][tid] = a6; sacc[7][tid] = a7;
    __syncthreads();

    // stage 1: per-wave partials. slot m=(j<<2)|ds covers dims 4m..4m+3;
    // contributors for wave g: lanes es*4+ds (es=0..15), reg j.
    if (tid < 128) {
        int g = tid >> 5, m = tid & 31, j = m >> 2, ds = m & 3;
        float4 s = make_float4(0.f, 0.f, 0.f, 0.f);
#pragma unroll
        for (int es = 0; es < 16; ++es) {
            float4 p = sacc[j][(g << 6) + (es << 2) + ds];
            s.x += p.x; s.y += p.y; s.z += p.z; s.w += p.w;
        }
        pm[g][m] = s;
    }
    __syncthreads();
    // stage 2: combine 4 waves, normalize, write
    if (tid < 32) {
        float4 p0 = pm[0][tid], p1 = pm[1][tid], p2 = pm[2][tid], p3 = pm[3][tid];
        float4 rr;
        rr.x = p0.x + p1.x + p2.x + p3.x;
        rr.y = p0.y + p1.y + p2.y + p3.y;
        rr.z = p0.z + p1.z + p2.z + p3.z;
        rr.w = p0.w + p1.w + p2.w + p3.w;
        float denom = (dnw[0] + dnw[1] + dnw[2] + dnw[3]) * 0.25f;
        float rden = denom > 0.f ? 1.0f / denom : 0.f;
        rr.x *= rden; rr.y *= rden; rr.z *= rden; rr.w *= rden;
        ((float4*)out)[(size_t)br * 32 + tid] = rr;
    }
}

extern "C" void kernel_launch(void* const* d_in, const int* in_sizes, int n_in,
                              void* d_out, int out_size, void* d_ws, size_t ws_size,
                              hipStream_t stream) {
    const float* nodes_in = (const float*)d_in[0];   // (B,N,H) f32
    const float* adj      = (const float*)d_in[1];   // (B,E,N) f32, binary
    const float* w1       = (const float*)d_in[2];   // (H+1)
    const float* w2       = (const float*)d_in[3];   // (H+1)

    char* ws = (char*)d_ws;
    size_t off = 0;
    u16* row_idx = (u16*)(ws + off); off += (size_t)B_ * E_ * CAP * sizeof(u16);
    u16* col_idx = (u16*)(ws + off); off += (size_t)B_ * N_ * CAP * sizeof(u16);
    int* row_cnt = (int*)(ws + off); off += (size_t)B_ * E_ * sizeof(int);
    int* col_cnt = (int*)(ws + off); off += (size_t)B_ * N_ * sizeof(int);
    int* cnt_chunk = (int*)(ws + off); off += (size_t)B_ * NC * N_ * sizeof(int);
    int* off_chunk = (int*)(ws + off); off += (size_t)B_ * NC * N_ * sizeof(int);

    float* out_nodes = (float*)d_out;                       // (B,N,H)
    float* out_edge  = out_nodes + (size_t)B_ * N_ * H_;    // (B,E,H)

    build_rows<<<dim3(B_ * E_), dim3(256), 0, stream>>>(adj, row_idx, row_cnt);
    col_count <<<dim3(B_ * NC * 4), dim3(256), 0, stream>>>(adj, cnt_chunk);
    col_prefix<<<dim3(B_ * N_ / 256), dim3(256), 0, stream>>>(cnt_chunk, off_chunk, col_cnt);
    col_place <<<dim3(B_ * NC * 4), dim3(256), 0, stream>>>(adj, off_chunk, col_idx);
    edge_init <<<dim3(B_ * E_), dim3(256), 0, stream>>>(nodes_in, row_idx, row_cnt, out_edge);

    const float* ncur = nodes_in;
    for (int s = 0; s < 2; ++s) {
        attn_gather<<<dim3(B_ * E_), dim3(256), 0, stream>>>(
            out_edge, ncur, w1, row_idx, row_cnt, out_edge);
        attn_gather<<<dim3(B_ * N_), dim3(256), 0, stream>>>(
            ncur, out_edge, w2, col_idx, col_cnt, out_nodes);
        ncur = out_nodes;
    }
}

// Round 9
// 292.282 us; speedup vs baseline: 1.1995x; 1.1995x over previous
//
#include <hip/hip_runtime.h>
#include <cstdint>
#include <cstddef>

#define B_ 16
#define E_ 1024
#define N_ 1024
#define H_ 128
#define CAP 192   // max nonzeros per row/col; Binomial(1024,0.1): mean 102, std 9.6 -> 192 = 9.3 sigma
#define NC 16     // e-chunks for column build
#define EC 64     // E_/NC

typedef unsigned short u16;

#define UPK2(u, flo, fhi) \
    flo = __uint_as_float((u) << 16); fhi = __uint_as_float((u) & 0xffff0000u)

__device__ __forceinline__ u16 f2bf(float f) {   // RTNE float->bf16
    unsigned u = __float_as_uint(f);
    return (u16)((u + 0x7fffu + ((u >> 16) & 1u)) >> 16);
}

__device__ __forceinline__ float wave_sum64(float v) {
    v += __shfl_xor(v, 32);
    v += __shfl_xor(v, 16);
    v += __shfl_xor(v, 8);
    v += __shfl_xor(v, 4);
    v += __shfl_xor(v, 2);
    v += __shfl_xor(v, 1);
    return v;
}

// Row nonzero lists: one block per (b,e). Coalesced, ordered (ascending n).
__global__ void build_rows(const float* __restrict__ adj,
                           u16* __restrict__ idx, int* __restrict__ cnt_out) {
    int be = blockIdx.x;                      // b*E + e
    const float* row = adj + (size_t)be * N_;
    __shared__ int wcnt[4];
    __shared__ int base;
    int tid = threadIdx.x, lane = tid & 63, wv = tid >> 6;
    if (tid == 0) base = 0;
    __syncthreads();
    for (int c0 = 0; c0 < N_; c0 += 256) {
        float v = row[c0 + tid];
        unsigned long long m = __ballot(v != 0.0f);
        if (lane == 0) wcnt[wv] = __popcll(m);
        __syncthreads();
        int pos = base;
        for (int w = 0; w < wv; ++w) pos += wcnt[w];
        pos += __popcll(m & ((1ull << lane) - 1ull));
        if (v != 0.0f && pos < CAP)
            idx[(size_t)be * CAP + pos] = (u16)(c0 + tid);
        __syncthreads();
        if (tid == 0) base += wcnt[0] + wcnt[1] + wcnt[2] + wcnt[3];
        __syncthreads();
    }
    if (tid == 0) cnt_out[be] = base < CAP ? base : CAP;
}

// --- Column lists, 3-phase parallel, deterministic (ascending e) ---
__global__ void col_count(const float* __restrict__ adj, int* __restrict__ cnt_chunk) {
    int blk = blockIdx.x;
    int ng = blk & 3;                 // n-group
    int c  = (blk >> 2) & (NC - 1);   // e-chunk
    int b  = blk >> 6;
    int n = (ng << 8) + threadIdx.x;
    const float* base = adj + ((size_t)(b * E_ + c * EC)) * N_ + n;
    int cc = 0;
#pragma unroll 8
    for (int e = 0; e < EC; ++e)
        cc += (base[(size_t)e * N_] != 0.0f);
    cnt_chunk[(size_t)(b * NC + c) * N_ + n] = cc;
}

__global__ void col_prefix(const int* __restrict__ cnt_chunk,
                           int* __restrict__ off_chunk, int* __restrict__ cnt_out) {
    int idx = blockIdx.x * 256 + threadIdx.x;   // b*N + n
    int b = idx >> 10, n = idx & 1023;
    int run = 0;
    for (int c = 0; c < NC; ++c) {
        size_t p = (size_t)(b * NC + c) * N_ + n;
        off_chunk[p] = run;
        run += cnt_chunk[p];
    }
    cnt_out[idx] = run < CAP ? run : CAP;
}

__global__ void col_place(const float* __restrict__ adj,
                          const int* __restrict__ off_chunk, u16* __restrict__ idx) {
    int blk = blockIdx.x;
    int ng = blk & 3;
    int c  = (blk >> 2) & (NC - 1);
    int b  = blk >> 6;
    int n = (ng << 8) + threadIdx.x;
    const float* base = adj + ((size_t)(b * E_ + c * EC)) * N_ + n;
    int pos = off_chunk[(size_t)(b * NC + c) * N_ + n];
    u16* lst = idx + ((size_t)b * N_ + n) * CAP;
    for (int e = 0; e < EC; ++e) {
        if (base[(size_t)e * N_] != 0.0f) {
            if (pos < CAP) lst[pos] = (u16)(c * EC + e);
            ++pos;
        }
    }
}

// One-time fp32 -> bf16 copy (nodes). 4 elems/thread.
__global__ void to_bf16(const float* __restrict__ in, u16* __restrict__ out) {
    int i = blockIdx.x * 256 + threadIdx.x;     // float4 index
    float4 v = ((const float4*)in)[i];
    ushort4 r;
    r.x = f2bf(v.x); r.y = f2bf(v.y); r.z = f2bf(v.z); r.w = f2bf(v.w);
    ((ushort4*)out)[i] = r;
}

// edge_init[b,e,:] = mean of incident node rows, gathered from bf16 nodes.
__global__ void edge_init(const u16* __restrict__ nodes_bf,
                          const u16* __restrict__ ridx, const int* __restrict__ rcnt,
                          float* __restrict__ edge) {
    int be = blockIdx.x;
    int b = be >> 10;
    int tid = threadIdx.x, d4 = tid & 31, h = tid >> 5;
    __shared__ u16 sidx[CAP];
    __shared__ float4 part4[256];
    int cnt = rcnt[be];
    for (int i = tid; i < cnt; i += 256) sidx[i] = ridx[(size_t)be * CAP + i];
    __syncthreads();
    const uint2* nb2 = (const uint2*)(nodes_bf + (size_t)b * N_ * H_);
    float4 acc = make_float4(0.f, 0.f, 0.f, 0.f);
    for (int i = h; i < cnt; i += 8) {
        uint2 u = nb2[(unsigned)sidx[i] * 32 + d4];
        float f0, f1, f2, f3;
        UPK2(u.x, f0, f1); UPK2(u.y, f2, f3);
        acc.x += f0; acc.y += f1; acc.z += f2; acc.w += f3;
    }
    part4[tid] = acc;
    __syncthreads();
    if (tid < 32) {
        float4 r = make_float4(0.f, 0.f, 0.f, 0.f);
#pragma unroll
        for (int k = 0; k < 8; ++k) {
            float4 p = part4[tid + (k << 5)];
            r.x += p.x; r.y += p.y; r.z += p.z; r.w += p.w;
        }
        float inv = 1.0f / (float)(cnt > 0 ? cnt : 1);
        r.x *= inv; r.y *= inv; r.z *= inv; r.w *= inv;
        ((float4*)edge)[(size_t)be * 32 + tid] = r;
    }
}

// Single-touch fused masked-softmax attention, bf16 KV gather (r6 structure).
// 8 lanes/entry, lane dsub holds CONTIGUOUS dims [16*dsub,16*dsub+16) as
// 2 uint4 bf16 loads (32 B/lane vs 64 fp32 -> halves L2 gather traffic).
// Unpack->fp32, dual dot chains, 3-level shfl, leaky, exp2 (q prescaled by
// log2e; no max shift, r5-validated), fp32 register accumulate.
// Merge: sacc[j][tid] (16 B stride, conflict-free) -> single-stage merge.
// Epilogue writes fp32 row AND bf16 row (bf16 feeds next phase's KV gather).
// Safe for qsrc == out (block reads only its own q row, writes only its row).
// XCD swizzle: batch b on XCD b%8 -> per-XCD kv footprint L2-resident.
__global__ void attn_gather(const float* __restrict__ qsrc,
                            const u16* __restrict__ kv_bf,
                            const float* __restrict__ w,
                            const u16* __restrict__ lidx, const int* __restrict__ lcnt,
                            float* __restrict__ out, u16* __restrict__ out_bf) {
    int x = blockIdx.x;
    int xcd = x & 7;
    int jb = x >> 3;                     // 0..2047
    int b = xcd + ((jb >> 10) << 3);     // batches {xcd, xcd+8}
    int rrow = jb & 1023;
    int br = (b << 10) + rrow;
    int tid = threadIdx.x, lane = tid & 63, wv = tid >> 6;   // 256 threads
    __shared__ float qsh[H_];
    __shared__ u16 sidx[CAP];
    __shared__ float4 sacc[4][256];      // [reg j][thread], conflict-free b128
    __shared__ float dnw[4];
    int cnt = lcnt[br];
    for (int i = tid; i < cnt; i += 256) sidx[i] = lidx[(size_t)br * CAP + i];
    if (tid < H_) qsh[tid] = qsrc[(size_t)br * H_ + tid] * w[tid] * 1.44269504f;
    __syncthreads();
    float wb = w[H_] * 1.44269504f;
    const uint4* kb4 = (const uint4*)(kv_bf + (size_t)b * 1024 * H_);

    int esub = lane >> 3, dsub = lane & 7;   // entry-in-wave, d-slice
    // lane covers dims [16*dsub, 16*dsub+16): q as 4 contiguous float4
    float4 qr0 = ((const float4*)qsh)[(dsub << 2) + 0];
    float4 qr1 = ((const float4*)qsh)[(dsub << 2) + 1];
    float4 qr2 = ((const float4*)qsh)[(dsub << 2) + 2];
    float4 qr3 = ((const float4*)qsh)[(dsub << 2) + 3];
    float4 a0 = make_float4(0.f, 0.f, 0.f, 0.f);
    float4 a1 = a0, a2 = a0, a3 = a0;
    float dpart = 0.f;
    int ibase = (wv << 3) + esub;

    for (int i0 = 0; i0 < cnt; i0 += 32) {
        int i = i0 + ibase;
        unsigned ro = (unsigned)((i < cnt) ? sidx[i] : 0) * 16 + (dsub << 1);
        uint4 g0 = kb4[ro];
        uint4 g1 = kb4[ro + 1];
        float f0, f1, f2, f3, f4, f5, f6, f7;
        float f8, f9, f10, f11, f12, f13, f14, f15;
        UPK2(g0.x, f0, f1);   UPK2(g0.y, f2, f3);
        UPK2(g0.z, f4, f5);   UPK2(g0.w, f6, f7);
        UPK2(g1.x, f8, f9);   UPK2(g1.y, f10, f11);
        UPK2(g1.z, f12, f13); UPK2(g1.w, f14, f15);
        float dA = 0.f, dB = 0.f;
        dA = fmaf(f0, qr0.x, dA);  dB = fmaf(f1, qr0.y, dB);
        dA = fmaf(f2, qr0.z, dA);  dB = fmaf(f3, qr0.w, dB);
        dA = fmaf(f4, qr1.x, dA);  dB = fmaf(f5, qr1.y, dB);
        dA = fmaf(f6, qr1.z, dA);  dB = fmaf(f7, qr1.w, dB);
        dA = fmaf(f8, qr2.x, dA);  dB = fmaf(f9, qr2.y, dB);
        dA = fmaf(f10, qr2.z, dA); dB = fmaf(f11, qr2.w, dB);
        dA = fmaf(f12, qr3.x, dA); dB = fmaf(f13, qr3.y, dB);
        dA = fmaf(f14, qr3.z, dA); dB = fmaf(f15, qr3.w, dB);
        float d = dA + dB;
        d += __shfl_xor(d, 1);
        d += __shfl_xor(d, 2);
        d += __shfl_xor(d, 4);           // all 8 lanes of entry hold full dot
        float p = d + wb;
        p = p >= 0.f ? p : 0.2f * p;     // LeakyReLU(0.2), commutes with log2e scale
        float ww = (i < cnt) ? exp2f(p) : 0.f;
        dpart += ww;
        a0.x = fmaf(ww, f0, a0.x);  a0.y = fmaf(ww, f1, a0.y);
        a0.z = fmaf(ww, f2, a0.z);  a0.w = fmaf(ww, f3, a0.w);
        a1.x = fmaf(ww, f4, a1.x);  a1.y = fmaf(ww, f5, a1.y);
        a1.z = fmaf(ww, f6, a1.z);  a1.w = fmaf(ww, f7, a1.w);
        a2.x = fmaf(ww, f8, a2.x);  a2.y = fmaf(ww, f9, a2.y);
        a2.z = fmaf(ww, f10, a2.z); a2.w = fmaf(ww, f11, a2.w);
        a3.x = fmaf(ww, f12, a3.x); a3.y = fmaf(ww, f13, a3.y);
        a3.z = fmaf(ww, f14, a3.z); a3.w = fmaf(ww, f15, a3.w);
    }

    // per-wave denom (each entry counted by its 8 lanes -> /8 at the end)
    dpart = wave_sum64(dpart);
    if (lane == 0) dnw[wv] = dpart;
    sacc[0][tid] = a0; sacc[1][tid] = a1; sacc[2][tid] = a2; sacc[3][tid] = a3;
    __syncthreads();

    // merge: output float4-slot m covers dims 4m..4m+3; ds=m>>2, j=m&3;
    // contributors: threads wv2*64 + es*8 + ds (es=0..7), reg j.
    if (tid < 32) {
        int ds = tid >> 2, j = tid & 3;
        float4 rr = make_float4(0.f, 0.f, 0.f, 0.f);
#pragma unroll
        for (int wv2 = 0; wv2 < 4; ++wv2)
#pragma unroll
            for (int es = 0; es < 8; ++es) {
                float4 p = sacc[j][(wv2 << 6) + (es << 3) + ds];
                rr.x += p.x; rr.y += p.y; rr.z += p.z; rr.w += p.w;
            }
        float denom = (dnw[0] + dnw[1] + dnw[2] + dnw[3]) * 0.125f;
        float rden = denom > 0.f ? 1.0f / denom : 0.f;
        rr.x *= rden; rr.y *= rden; rr.z *= rden; rr.w *= rden;
        int m = (ds << 2) + j;           // wait: slot m has ds=m>>2, j=m&3
        ((float4*)out)[(size_t)br * 32 + m] = rr;
        ushort4 hb;
        hb.x = f2bf(rr.x); hb.y = f2bf(rr.y); hb.z = f2bf(rr.z); hb.w = f2bf(rr.w);
        ((ushort4*)out_bf)[(size_t)br * 32 + m] = hb;
    }
}

extern "C" void kernel_launch(void* const* d_in, const int* in_sizes, int n_in,
                              void* d_out, int out_size, void* d_ws, size_t ws_size,
                              hipStream_t stream) {
    const float* nodes_in = (const float*)d_in[0];   // (B,N,H) f32
    const float* adj      = (const float*)d_in[1];   // (B,E,N) f32, binary
    const float* w1       = (const float*)d_in[2];   // (H+1)
    const float* w2       = (const float*)d_in[3];   // (H+1)

    char* ws = (char*)d_ws;
    size_t off = 0;
    u16* row_idx = (u16*)(ws + off); off += (size_t)B_ * E_ * CAP * sizeof(u16);
    u16* col_idx = (u16*)(ws + off); off += (size_t)B_ * N_ * CAP * sizeof(u16);
    int* row_cnt = (int*)(ws + off); off += (size_t)B_ * E_ * sizeof(int);
    int* col_cnt = (int*)(ws + off); off += (size_t)B_ * N_ * sizeof(int);
    int* cnt_chunk = (int*)(ws + off); off += (size_t)B_ * NC * N_ * sizeof(int);
    int* off_chunk = (int*)(ws + off); off += (size_t)B_ * NC * N_ * sizeof(int);
    u16* nodes_bf = (u16*)(ws + off); off += (size_t)B_ * N_ * H_ * sizeof(u16);
    u16* edge_bf  = (u16*)(ws + off); off += (size_t)B_ * E_ * H_ * sizeof(u16);

    float* out_nodes = (float*)d_out;                       // (B,N,H)
    float* out_edge  = out_nodes + (size_t)B_ * N_ * H_;    // (B,E,H)

    build_rows<<<dim3(B_ * E_), dim3(256), 0, stream>>>(adj, row_idx, row_cnt);
    col_count <<<dim3(B_ * NC * 4), dim3(256), 0, stream>>>(adj, cnt_chunk);
    col_prefix<<<dim3(B_ * N_ / 256), dim3(256), 0, stream>>>(cnt_chunk, off_chunk, col_cnt);
    col_place <<<dim3(B_ * NC * 4), dim3(256), 0, stream>>>(adj, off_chunk, col_idx);
    to_bf16   <<<dim3(B_ * N_ * H_ / 1024), dim3(256), 0, stream>>>(nodes_in, nodes_bf);
    edge_init <<<dim3(B_ * E_), dim3(256), 0, stream>>>(nodes_bf, row_idx, row_cnt, out_edge);

    const float* ncur = nodes_in;
    for (int s = 0; s < 2; ++s) {
        // edge = alpha(edge_q, nodes_kv); writes fp32 out_edge + bf16 edge_bf
        attn_gather<<<dim3(B_ * E_), dim3(256), 0, stream>>>(
            out_edge, nodes_bf, w1, row_idx, row_cnt, out_edge, edge_bf);
        // nodes = beta(nodes_q, edge_kv); writes fp32 out_nodes + bf16 nodes_bf
        attn_gather<<<dim3(B_ * N_), dim3(256), 0, stream>>>(
            ncur, edge_bf, w2, col_idx, col_cnt, out_nodes, nodes_bf);
        ncur = out_nodes;
    }
}

// Round 10
// 267.648 us; speedup vs baseline: 1.3099x; 1.0920x over previous
//
#include <hip/hip_runtime.h>
#include <cstdint>
#include <cstddef>

#define B_ 16
#define E_ 1024
#define N_ 1024
#define H_ 128
#define CAP 192   // max nonzeros per row/col; Binomial(1024,0.1): mean 102, std 9.6 -> 192 = 9.3 sigma
#define NC 16     // e-chunks for column build
#define EC 64     // E_/NC

typedef unsigned short u16;

#define UPK2(u, flo, fhi) \
    flo = __uint_as_float((u) << 16); fhi = __uint_as_float((u) & 0xffff0000u)

__device__ __forceinline__ u16 f2bf(float f) {   // RTNE float->bf16
    unsigned u = __float_as_uint(f);
    return (u16)((u + 0x7fffu + ((u >> 16) & 1u)) >> 16);
}

__device__ __forceinline__ float wave_sum64(float v) {
    v += __shfl_xor(v, 32);
    v += __shfl_xor(v, 16);
    v += __shfl_xor(v, 8);
    v += __shfl_xor(v, 4);
    v += __shfl_xor(v, 2);
    v += __shfl_xor(v, 1);
    return v;
}

// Row nonzero lists: one block per (b,e). Coalesced, ordered (ascending n).
__global__ void build_rows(const float* __restrict__ adj,
                           u16* __restrict__ idx, int* __restrict__ cnt_out) {
    int be = blockIdx.x;                      // b*E + e
    const float* row = adj + (size_t)be * N_;
    __shared__ int wcnt[4];
    __shared__ int base;
    int tid = threadIdx.x, lane = tid & 63, wv = tid >> 6;
    if (tid == 0) base = 0;
    __syncthreads();
    for (int c0 = 0; c0 < N_; c0 += 256) {
        float v = row[c0 + tid];
        unsigned long long m = __ballot(v != 0.0f);
        if (lane == 0) wcnt[wv] = __popcll(m);
        __syncthreads();
        int pos = base;
        for (int w = 0; w < wv; ++w) pos += wcnt[w];
        pos += __popcll(m & ((1ull << lane) - 1ull));
        if (v != 0.0f && pos < CAP)
            idx[(size_t)be * CAP + pos] = (u16)(c0 + tid);
        __syncthreads();
        if (tid == 0) base += wcnt[0] + wcnt[1] + wcnt[2] + wcnt[3];
        __syncthreads();
    }
    if (tid == 0) cnt_out[be] = base < CAP ? base : CAP;
}

// --- Column lists, 3-phase parallel, deterministic (ascending e) ---
__global__ void col_count(const float* __restrict__ adj, int* __restrict__ cnt_chunk) {
    int blk = blockIdx.x;
    int ng = blk & 3;                 // n-group
    int c  = (blk >> 2) & (NC - 1);   // e-chunk
    int b  = blk >> 6;
    int n = (ng << 8) + threadIdx.x;
    const float* base = adj + ((size_t)(b * E_ + c * EC)) * N_ + n;
    int cc = 0;
#pragma unroll 8
    for (int e = 0; e < EC; ++e)
        cc += (base[(size_t)e * N_] != 0.0f);
    cnt_chunk[(size_t)(b * NC + c) * N_ + n] = cc;
}

__global__ void col_prefix(const int* __restrict__ cnt_chunk,
                           int* __restrict__ off_chunk, int* __restrict__ cnt_out) {
    int idx = blockIdx.x * 256 + threadIdx.x;   // b*N + n
    int b = idx >> 10, n = idx & 1023;
    int run = 0;
    for (int c = 0; c < NC; ++c) {
        size_t p = (size_t)(b * NC + c) * N_ + n;
        off_chunk[p] = run;
        run += cnt_chunk[p];
    }
    cnt_out[idx] = run < CAP ? run : CAP;
}

__global__ void col_place(const float* __restrict__ adj,
                          const int* __restrict__ off_chunk, u16* __restrict__ idx) {
    int blk = blockIdx.x;
    int ng = blk & 3;
    int c  = (blk >> 2) & (NC - 1);
    int b  = blk >> 6;
    int n = (ng << 8) + threadIdx.x;
    const float* base = adj + ((size_t)(b * E_ + c * EC)) * N_ + n;
    int pos = off_chunk[(size_t)(b * NC + c) * N_ + n];
    u16* lst = idx + ((size_t)b * N_ + n) * CAP;
    for (int e = 0; e < EC; ++e) {
        if (base[(size_t)e * N_] != 0.0f) {
            if (pos < CAP) lst[pos] = (u16)(c * EC + e);
            ++pos;
        }
    }
}

// One-time fp32 -> bf16 copy (nodes). 4 elems/thread.
__global__ void to_bf16(const float* __restrict__ in, u16* __restrict__ out) {
    int i = blockIdx.x * 256 + threadIdx.x;     // float4 index
    float4 v = ((const float4*)in)[i];
    ushort4 r;
    r.x = f2bf(v.x); r.y = f2bf(v.y); r.z = f2bf(v.z); r.w = f2bf(v.w);
    ((ushort4*)out)[i] = r;
}

// edge_init[b,e,:] = mean of incident node rows, gathered from bf16 nodes.
__global__ void edge_init(const u16* __restrict__ nodes_bf,
                          const u16* __restrict__ ridx, const int* __restrict__ rcnt,
                          float* __restrict__ edge) {
    int be = blockIdx.x;
    int b = be >> 10;
    int tid = threadIdx.x, d4 = tid & 31, h = tid >> 5;
    __shared__ u16 sidx[CAP];
    __shared__ float4 part4[256];
    int cnt = rcnt[be];
    for (int i = tid; i < cnt; i += 256) sidx[i] = ridx[(size_t)be * CAP + i];
    __syncthreads();
    const uint2* nb2 = (const uint2*)(nodes_bf + (size_t)b * N_ * H_);
    float4 acc = make_float4(0.f, 0.f, 0.f, 0.f);
    for (int i = h; i < cnt; i += 8) {
        uint2 u = nb2[(unsigned)sidx[i] * 32 + d4];
        float f0, f1, f2, f3;
        UPK2(u.x, f0, f1); UPK2(u.y, f2, f3);
        acc.x += f0; acc.y += f1; acc.z += f2; acc.w += f3;
    }
    part4[tid] = acc;
    __syncthreads();
    if (tid < 32) {
        float4 r = make_float4(0.f, 0.f, 0.f, 0.f);
#pragma unroll
        for (int k = 0; k < 8; ++k) {
            float4 p = part4[tid + (k << 5)];
            r.x += p.x; r.y += p.y; r.z += p.z; r.w += p.w;
        }
        float inv = 1.0f / (float)(cnt > 0 ? cnt : 1);
        r.x *= inv; r.y *= inv; r.z *= inv; r.w *= inv;
        ((float4*)edge)[(size_t)be * 32 + tid] = r;
    }
}

// Wave-per-row fused masked-softmax attention, bf16 KV gather.
// 256-thr block = 4 waves = 4 independent rows; NO __syncthreads, no block
// merge. Per wave-round: 8 entries, 8 lanes each (lane dsub holds dims
// [16*dsub,16*dsub+16) as 2 uint4 bf16). Unpack->fp32, dual dot chains,
// 3-level shfl, leaky, exp2 (q prescaled by log2e; no max shift,
// r5-validated), fp32 register accumulate. 1-deep register prefetch of the
// next round's KV. Merge: 3 shfl_xor levels (8/16/32) over the 16 acc
// floats; lanes 0..7 write fp32 + bf16 rows.
// Rounds = ceil(cnt/8) -> ~2% tail waste vs 25% in the 4-wave/row form.
// Safe for qsrc == out (wave reads only its own q row, writes only its row).
// XCD swizzle: batch b on XCD b%8 -> per-XCD kv footprint L2-resident.
__global__ void __launch_bounds__(256, 4)
attn_gather(const float* __restrict__ qsrc,
            const u16* __restrict__ kv_bf,
            const float* __restrict__ w,
            const u16* __restrict__ lidx, const int* __restrict__ lcnt,
            float* __restrict__ out, u16* __restrict__ out_bf) {
    int x = blockIdx.x;                  // 4096 blocks
    int xcd = x & 7;
    int j = x >> 3;                      // 0..511
    int b = xcd + ((j >> 8) << 3);       // batches {xcd, xcd+8}
    int rg = (j & 255) << 2;             // 4-row group
    int tid = threadIdx.x, lane = tid & 63, wv = tid >> 6;
    int br = (b << 10) + rg + wv;        // this wave's row
    __shared__ u16 sidx[4][CAP];
    int cnt = lcnt[br];
    for (int i = lane; i < cnt; i += 64) sidx[wv][i] = lidx[(size_t)br * CAP + i];

    int esub = lane >> 3, dsub = lane & 7;   // entry-in-round, d-slice
    // q*w*log2e straight to registers (dims [16*dsub,16*dsub+16))
    const float4* qp = (const float4*)(qsrc + (size_t)br * H_);
    const float4* wp = (const float4*)w;
    float4 qr0, qr1, qr2, qr3;
    {
        float4 q0 = qp[(dsub << 2) + 0], w0 = wp[(dsub << 2) + 0];
        float4 q1 = qp[(dsub << 2) + 1], w1 = wp[(dsub << 2) + 1];
        float4 q2 = qp[(dsub << 2) + 2], w2 = wp[(dsub << 2) + 2];
        float4 q3 = qp[(dsub << 2) + 3], w3 = wp[(dsub << 2) + 3];
        const float L2E = 1.44269504f;
        qr0.x = q0.x * w0.x * L2E; qr0.y = q0.y * w0.y * L2E;
        qr0.z = q0.z * w0.z * L2E; qr0.w = q0.w * w0.w * L2E;
        qr1.x = q1.x * w1.x * L2E; qr1.y = q1.y * w1.y * L2E;
        qr1.z = q1.z * w1.z * L2E; qr1.w = q1.w * w1.w * L2E;
        qr2.x = q2.x * w2.x * L2E; qr2.y = q2.y * w2.y * L2E;
        qr2.z = q2.z * w2.z * L2E; qr2.w = q2.w * w2.w * L2E;
        qr3.x = q3.x * w3.x * L2E; qr3.y = q3.y * w3.y * L2E;
        qr3.z = q3.z * w3.z * L2E; qr3.w = q3.w * w3.w * L2E;
    }
    float wb = w[H_] * 1.44269504f;
    const uint4* kb4 = (const uint4*)(kv_bf + (size_t)b * 1024 * H_);

    float4 a0 = make_float4(0.f, 0.f, 0.f, 0.f);
    float4 a1 = a0, a2 = a0, a3 = a0;
    float dpart = 0.f;

    // prime: load round 0's KV (clamped index; sidx just written by this wave)
    unsigned ro = (unsigned)((esub < cnt) ? sidx[wv][esub] : 0) * 16 + (dsub << 1);
    uint4 g0 = kb4[ro];
    uint4 g1 = kb4[ro + 1];

    for (int i0 = 0; i0 < cnt; i0 += 8) {
        // prefetch next round (always-load, clamped)
        int inx = i0 + 8 + esub;
        unsigned rn = (unsigned)((inx < cnt) ? sidx[wv][inx] : 0) * 16 + (dsub << 1);
        uint4 n0 = kb4[rn];
        uint4 n1 = kb4[rn + 1];
        // compute with current
        int i = i0 + esub;
        float f0, f1, f2, f3, f4, f5, f6, f7;
        float f8, f9, f10, f11, f12, f13, f14, f15;
        UPK2(g0.x, f0, f1);   UPK2(g0.y, f2, f3);
        UPK2(g0.z, f4, f5);   UPK2(g0.w, f6, f7);
        UPK2(g1.x, f8, f9);   UPK2(g1.y, f10, f11);
        UPK2(g1.z, f12, f13); UPK2(g1.w, f14, f15);
        float dA = 0.f, dB = 0.f;
        dA = fmaf(f0, qr0.x, dA);  dB = fmaf(f1, qr0.y, dB);
        dA = fmaf(f2, qr0.z, dA);  dB = fmaf(f3, qr0.w, dB);
        dA = fmaf(f4, qr1.x, dA);  dB = fmaf(f5, qr1.y, dB);
        dA = fmaf(f6, qr1.z, dA);  dB = fmaf(f7, qr1.w, dB);
        dA = fmaf(f8, qr2.x, dA);  dB = fmaf(f9, qr2.y, dB);
        dA = fmaf(f10, qr2.z, dA); dB = fmaf(f11, qr2.w, dB);
        dA = fmaf(f12, qr3.x, dA); dB = fmaf(f13, qr3.y, dB);
        dA = fmaf(f14, qr3.z, dA); dB = fmaf(f15, qr3.w, dB);
        float d = dA + dB;
        d += __shfl_xor(d, 1);
        d += __shfl_xor(d, 2);
        d += __shfl_xor(d, 4);           // all 8 lanes of entry hold full dot
        float p = d + wb;
        p = p >= 0.f ? p : 0.2f * p;     // LeakyReLU(0.2), commutes with log2e scale
        float ww = (i < cnt) ? exp2f(p) : 0.f;
        dpart += ww;
        a0.x = fmaf(ww, f0, a0.x);  a0.y = fmaf(ww, f1, a0.y);
        a0.z = fmaf(ww, f2, a0.z);  a0.w = fmaf(ww, f3, a0.w);
        a1.x = fmaf(ww, f4, a1.x);  a1.y = fmaf(ww, f5, a1.y);
        a1.z = fmaf(ww, f6, a1.z);  a1.w = fmaf(ww, f7, a1.w);
        a2.x = fmaf(ww, f8, a2.x);  a2.y = fmaf(ww, f9, a2.y);
        a2.z = fmaf(ww, f10, a2.z); a2.w = fmaf(ww, f11, a2.w);
        a3.x = fmaf(ww, f12, a3.x); a3.y = fmaf(ww, f13, a3.y);
        a3.z = fmaf(ww, f14, a3.z); a3.w = fmaf(ww, f15, a3.w);
        g0 = n0; g1 = n1;
    }

    // intra-wave merge across esub groups (xor 8/16/32); all lanes end full.
#define RED3(f) f += __shfl_xor(f, 8); f += __shfl_xor(f, 16); f += __shfl_xor(f, 32)
    RED3(a0.x); RED3(a0.y); RED3(a0.z); RED3(a0.w);
    RED3(a1.x); RED3(a1.y); RED3(a1.z); RED3(a1.w);
    RED3(a2.x); RED3(a2.y); RED3(a2.z); RED3(a2.w);
    RED3(a3.x); RED3(a3.y); RED3(a3.z); RED3(a3.w);
#undef RED3
    float denom = wave_sum64(dpart) * 0.125f;   // each entry counted by 8 lanes
    float rden = denom > 0.f ? 1.0f / denom : 0.f;

    if (esub == 0) {                      // lanes 0..7, lane == dsub
        a0.x *= rden; a0.y *= rden; a0.z *= rden; a0.w *= rden;
        a1.x *= rden; a1.y *= rden; a1.z *= rden; a1.w *= rden;
        a2.x *= rden; a2.y *= rden; a2.z *= rden; a2.w *= rden;
        a3.x *= rden; a3.y *= rden; a3.z *= rden; a3.w *= rden;
        float4* op = (float4*)out + (size_t)br * 32 + (dsub << 2);
        op[0] = a0; op[1] = a1; op[2] = a2; op[3] = a3;
        ushort4* hp = (ushort4*)out_bf + (size_t)br * 32 + (dsub << 2);
        ushort4 h0, h1, h2, h3;
        h0.x = f2bf(a0.x); h0.y = f2bf(a0.y); h0.z = f2bf(a0.z); h0.w = f2bf(a0.w);
        h1.x = f2bf(a1.x); h1.y = f2bf(a1.y); h1.z = f2bf(a1.z); h1.w = f2bf(a1.w);
        h2.x = f2bf(a2.x); h2.y = f2bf(a2.y); h2.z = f2bf(a2.z); h2.w = f2bf(a2.w);
        h3.x = f2bf(a3.x); h3.y = f2bf(a3.y); h3.z = f2bf(a3.z); h3.w = f2bf(a3.w);
        hp[0] = h0; hp[1] = h1; hp[2] = h2; hp[3] = h3;
    }
}

extern "C" void kernel_launch(void* const* d_in, const int* in_sizes, int n_in,
                              void* d_out, int out_size, void* d_ws, size_t ws_size,
                              hipStream_t stream) {
    const float* nodes_in = (const float*)d_in[0];   // (B,N,H) f32
    const float* adj      = (const float*)d_in[1];   // (B,E,N) f32, binary
    const float* w1       = (const float*)d_in[2];   // (H+1)
    const float* w2       = (const float*)d_in[3];   // (H+1)

    char* ws = (char*)d_ws;
    size_t off = 0;
    u16* row_idx = (u16*)(ws + off); off += (size_t)B_ * E_ * CAP * sizeof(u16);
    u16* col_idx = (u16*)(ws + off); off += (size_t)B_ * N_ * CAP * sizeof(u16);
    int* row_cnt = (int*)(ws + off); off += (size_t)B_ * E_ * sizeof(int);
    int* col_cnt = (int*)(ws + off); off += (size_t)B_ * N_ * sizeof(int);
    int* cnt_chunk = (int*)(ws + off); off += (size_t)B_ * NC * N_ * sizeof(int);
    int* off_chunk = (int*)(ws + off); off += (size_t)B_ * NC * N_ * sizeof(int);
    u16* nodes_bf = (u16*)(ws + off); off += (size_t)B_ * N_ * H_ * sizeof(u16);
    u16* edge_bf  = (u16*)(ws + off); off += (size_t)B_ * E_ * H_ * sizeof(u16);

    float* out_nodes = (float*)d_out;                       // (B,N,H)
    float* out_edge  = out_nodes + (size_t)B_ * N_ * H_;    // (B,E,H)

    build_rows<<<dim3(B_ * E_), dim3(256), 0, stream>>>(adj, row_idx, row_cnt);
    col_count <<<dim3(B_ * NC * 4), dim3(256), 0, stream>>>(adj, cnt_chunk);
    col_prefix<<<dim3(B_ * N_ / 256), dim3(256), 0, stream>>>(cnt_chunk, off_chunk, col_cnt);
    col_place <<<dim3(B_ * NC * 4), dim3(256), 0, stream>>>(adj, off_chunk, col_idx);
    to_bf16   <<<dim3(B_ * N_ * H_ / 1024), dim3(256), 0, stream>>>(nodes_in, nodes_bf);
    edge_init <<<dim3(B_ * E_), dim3(256), 0, stream>>>(nodes_bf, row_idx, row_cnt, out_edge);

    const float* ncur = nodes_in;
    for (int s = 0; s < 2; ++s) {
        // edge = alpha(edge_q, nodes_kv); writes fp32 out_edge + bf16 edge_bf
        attn_gather<<<dim3(B_ * E_ / 4), dim3(256), 0, stream>>>(
            out_edge, nodes_bf, w1, row_idx, row_cnt, out_edge, edge_bf);
        // nodes = beta(nodes_q, edge_kv); writes fp32 out_nodes + bf16 nodes_bf
        attn_gather<<<dim3(B_ * N_ / 4), dim3(256), 0, stream>>>(
            ncur, edge_bf, w2, col_idx, col_cnt, out_nodes, nodes_bf);
        ncur = out_nodes;
    }
}

// Round 11
// 232.778 us; speedup vs baseline: 1.5061x; 1.1498x over previous
//
#include <hip/hip_runtime.h>
#include <cstdint>
#include <cstddef>

#define B_ 16
#define E_ 1024
#define N_ 1024
#define H_ 128
#define CAP 192   // max nonzeros per row/col; Binomial(1024,0.1): mean 102, std 9.6 -> 192 = 9.3 sigma
#define NC 32     // e-chunks for column build (32 -> shorter latency chains)
#define EC 32     // E_/NC

typedef unsigned short u16;

#define UPK2(u, flo, fhi) \
    flo = __uint_as_float((u) << 16); fhi = __uint_as_float((u) & 0xffff0000u)

__device__ __forceinline__ u16 f2bf(float f) {   // RTNE float->bf16
    unsigned u = __float_as_uint(f);
    return (u16)((u + 0x7fffu + ((u >> 16) & 1u)) >> 16);
}

__device__ __forceinline__ float wave_sum64(float v) {
    v += __shfl_xor(v, 32);
    v += __shfl_xor(v, 16);
    v += __shfl_xor(v, 8);
    v += __shfl_xor(v, 4);
    v += __shfl_xor(v, 2);
    v += __shfl_xor(v, 1);
    return v;
}

// Row nonzero lists: one block per (b,e). Coalesced, ordered (ascending n).
__global__ void build_rows(const float* __restrict__ adj,
                           u16* __restrict__ idx, int* __restrict__ cnt_out) {
    int be = blockIdx.x;                      // b*E + e
    const float* row = adj + (size_t)be * N_;
    __shared__ int wcnt[4];
    __shared__ int base;
    int tid = threadIdx.x, lane = tid & 63, wv = tid >> 6;
    if (tid == 0) base = 0;
    __syncthreads();
    for (int c0 = 0; c0 < N_; c0 += 256) {
        float v = row[c0 + tid];
        unsigned long long m = __ballot(v != 0.0f);
        if (lane == 0) wcnt[wv] = __popcll(m);
        __syncthreads();
        int pos = base;
        for (int w = 0; w < wv; ++w) pos += wcnt[w];
        pos += __popcll(m & ((1ull << lane) - 1ull));
        if (v != 0.0f && pos < CAP)
            idx[(size_t)be * CAP + pos] = (u16)(c0 + tid);
        __syncthreads();
        if (tid == 0) base += wcnt[0] + wcnt[1] + wcnt[2] + wcnt[3];
        __syncthreads();
    }
    if (tid == 0) cnt_out[be] = base < CAP ? base : CAP;
}

// --- Column lists, 3-phase parallel, deterministic (ascending e) ---
__global__ void col_count(const float* __restrict__ adj, int* __restrict__ cnt_chunk) {
    int blk = blockIdx.x;
    int ng = blk & 3;                 // n-group
    int c  = (blk >> 2) & (NC - 1);   // e-chunk
    int b  = blk >> 7;                // blk/(NC*4)
    int n = (ng << 8) + threadIdx.x;
    const float* base = adj + ((size_t)(b * E_ + c * EC)) * N_ + n;
    int cc = 0;
#pragma unroll 8
    for (int e = 0; e < EC; ++e)
        cc += (base[(size_t)e * N_] != 0.0f);
    cnt_chunk[(size_t)(b * NC + c) * N_ + n] = cc;
}

__global__ void col_prefix(const int* __restrict__ cnt_chunk,
                           int* __restrict__ off_chunk, int* __restrict__ cnt_out) {
    int idx = blockIdx.x * 256 + threadIdx.x;   // b*N + n
    int b = idx >> 10, n = idx & 1023;
    int run = 0;
    for (int c = 0; c < NC; ++c) {
        size_t p = (size_t)(b * NC + c) * N_ + n;
        off_chunk[p] = run;
        run += cnt_chunk[p];
    }
    cnt_out[idx] = run < CAP ? run : CAP;
}

__global__ void col_place(const float* __restrict__ adj,
                          const int* __restrict__ off_chunk, u16* __restrict__ idx) {
    int blk = blockIdx.x;
    int ng = blk & 3;
    int c  = (blk >> 2) & (NC - 1);
    int b  = blk >> 7;
    int n = (ng << 8) + threadIdx.x;
    const float* base = adj + ((size_t)(b * E_ + c * EC)) * N_ + n;
    int pos = off_chunk[(size_t)(b * NC + c) * N_ + n];
    u16* lst = idx + ((size_t)b * N_ + n) * CAP;
    for (int e = 0; e < EC; ++e) {
        if (base[(size_t)e * N_] != 0.0f) {
            if (pos < CAP) lst[pos] = (u16)(c * EC + e);
            ++pos;
        }
    }
}

// One-time fp32 -> bf16 copy (nodes). 4 elems/thread.
__global__ void to_bf16(const float* __restrict__ in, u16* __restrict__ out) {
    int i = blockIdx.x * 256 + threadIdx.x;     // float4 index
    float4 v = ((const float4*)in)[i];
    ushort4 r;
    r.x = f2bf(v.x); r.y = f2bf(v.y); r.z = f2bf(v.z); r.w = f2bf(v.w);
    ((ushort4*)out)[i] = r;
}

// Wave-per-row edge_init: edge[b,e,:] = mean of incident bf16 node rows.
// Same gather skeleton as attn_gather (8 entries/round, 2 uint4/lane,
// 1-deep prefetch, 3-level shfl merge, no __syncthreads), minus scores.
__global__ void __launch_bounds__(256, 4)
edge_init(const u16* __restrict__ nodes_bf,
          const u16* __restrict__ ridx, const int* __restrict__ rcnt,
          float* __restrict__ edge) {
    int x = blockIdx.x;                  // B_*E_/4 = 4096
    int xcd = x & 7;
    int j = x >> 3;                      // 0..511
    int b = xcd + ((j >> 8) << 3);       // batches {xcd, xcd+8}
    int rg = (j & 255) << 2;
    int tid = threadIdx.x, lane = tid & 63, wv = tid >> 6;
    int be = (b << 10) + rg + wv;        // this wave's edge row
    __shared__ u16 sidx[4][CAP];
    int cnt = rcnt[be];
    for (int i = lane; i < cnt; i += 64) sidx[wv][i] = ridx[(size_t)be * CAP + i];

    int esub = lane >> 3, dsub = lane & 7;
    const uint4* kb4 = (const uint4*)(nodes_bf + (size_t)b * N_ * H_);
    float4 a0 = make_float4(0.f, 0.f, 0.f, 0.f);
    float4 a1 = a0, a2 = a0, a3 = a0;

    unsigned ro = (unsigned)((esub < cnt) ? sidx[wv][esub] : 0) * 16 + (dsub << 1);
    uint4 g0 = kb4[ro];
    uint4 g1 = kb4[ro + 1];

    for (int i0 = 0; i0 < cnt; i0 += 8) {
        int inx = i0 + 8 + esub;
        unsigned rn = (unsigned)((inx < cnt) ? sidx[wv][inx] : 0) * 16 + (dsub << 1);
        uint4 n0 = kb4[rn];
        uint4 n1 = kb4[rn + 1];
        int i = i0 + esub;
        float f0, f1, f2, f3, f4, f5, f6, f7;
        float f8, f9, f10, f11, f12, f13, f14, f15;
        UPK2(g0.x, f0, f1);   UPK2(g0.y, f2, f3);
        UPK2(g0.z, f4, f5);   UPK2(g0.w, f6, f7);
        UPK2(g1.x, f8, f9);   UPK2(g1.y, f10, f11);
        UPK2(g1.z, f12, f13); UPK2(g1.w, f14, f15);
        float ww = (i < cnt) ? 1.0f : 0.f;
        a0.x = fmaf(ww, f0, a0.x);  a0.y = fmaf(ww, f1, a0.y);
        a0.z = fmaf(ww, f2, a0.z);  a0.w = fmaf(ww, f3, a0.w);
        a1.x = fmaf(ww, f4, a1.x);  a1.y = fmaf(ww, f5, a1.y);
        a1.z = fmaf(ww, f6, a1.z);  a1.w = fmaf(ww, f7, a1.w);
        a2.x = fmaf(ww, f8, a2.x);  a2.y = fmaf(ww, f9, a2.y);
        a2.z = fmaf(ww, f10, a2.z); a2.w = fmaf(ww, f11, a2.w);
        a3.x = fmaf(ww, f12, a3.x); a3.y = fmaf(ww, f13, a3.y);
        a3.z = fmaf(ww, f14, a3.z); a3.w = fmaf(ww, f15, a3.w);
        g0 = n0; g1 = n1;
    }

#define RED3(f) f += __shfl_xor(f, 8); f += __shfl_xor(f, 16); f += __shfl_xor(f, 32)
    RED3(a0.x); RED3(a0.y); RED3(a0.z); RED3(a0.w);
    RED3(a1.x); RED3(a1.y); RED3(a1.z); RED3(a1.w);
    RED3(a2.x); RED3(a2.y); RED3(a2.z); RED3(a2.w);
    RED3(a3.x); RED3(a3.y); RED3(a3.z); RED3(a3.w);
#undef RED3
    if (esub == 0) {
        float inv = 1.0f / (float)(cnt > 0 ? cnt : 1);
        a0.x *= inv; a0.y *= inv; a0.z *= inv; a0.w *= inv;
        a1.x *= inv; a1.y *= inv; a1.z *= inv; a1.w *= inv;
        a2.x *= inv; a2.y *= inv; a2.z *= inv; a2.w *= inv;
        a3.x *= inv; a3.y *= inv; a3.z *= inv; a3.w *= inv;
        float4* op = (float4*)edge + (size_t)be * 32 + (dsub << 2);
        op[0] = a0; op[1] = a1; op[2] = a2; op[3] = a3;
    }
}

// Wave-per-row fused masked-softmax attention, bf16 KV gather (r9/r10 best).
// wbf=0 skips the bf16 shadow write (dead in the final beta dispatch).
__global__ void __launch_bounds__(256, 4)
attn_gather(const float* __restrict__ qsrc,
            const u16* __restrict__ kv_bf,
            const float* __restrict__ w,
            const u16* __restrict__ lidx, const int* __restrict__ lcnt,
            float* __restrict__ out, u16* __restrict__ out_bf, int wbf) {
    int x = blockIdx.x;                  // 4096 blocks
    int xcd = x & 7;
    int j = x >> 3;                      // 0..511
    int b = xcd + ((j >> 8) << 3);       // batches {xcd, xcd+8}
    int rg = (j & 255) << 2;             // 4-row group
    int tid = threadIdx.x, lane = tid & 63, wv = tid >> 6;
    int br = (b << 10) + rg + wv;        // this wave's row
    __shared__ u16 sidx[4][CAP];
    int cnt = lcnt[br];
    for (int i = lane; i < cnt; i += 64) sidx[wv][i] = lidx[(size_t)br * CAP + i];

    int esub = lane >> 3, dsub = lane & 7;   // entry-in-round, d-slice
    const float4* qp = (const float4*)(qsrc + (size_t)br * H_);
    const float4* wp = (const float4*)w;
    float4 qr0, qr1, qr2, qr3;
    {
        float4 q0 = qp[(dsub << 2) + 0], w0 = wp[(dsub << 2) + 0];
        float4 q1 = qp[(dsub << 2) + 1], w1 = wp[(dsub << 2) + 1];
        float4 q2 = qp[(dsub << 2) + 2], w2 = wp[(dsub << 2) + 2];
        float4 q3 = qp[(dsub << 2) + 3], w3 = wp[(dsub << 2) + 3];
        const float L2E = 1.44269504f;
        qr0.x = q0.x * w0.x * L2E; qr0.y = q0.y * w0.y * L2E;
        qr0.z = q0.z * w0.z * L2E; qr0.w = q0.w * w0.w * L2E;
        qr1.x = q1.x * w1.x * L2E; qr1.y = q1.y * w1.y * L2E;
        qr1.z = q1.z * w1.z * L2E; qr1.w = q1.w * w1.w * L2E;
        qr2.x = q2.x * w2.x * L2E; qr2.y = q2.y * w2.y * L2E;
        qr2.z = q2.z * w2.z * L2E; qr2.w = q2.w * w2.w * L2E;
        qr3.x = q3.x * w3.x * L2E; qr3.y = q3.y * w3.y * L2E;
        qr3.z = q3.z * w3.z * L2E; qr3.w = q3.w * w3.w * L2E;
    }
    float wb = w[H_] * 1.44269504f;
    const uint4* kb4 = (const uint4*)(kv_bf + (size_t)b * 1024 * H_);

    float4 a0 = make_float4(0.f, 0.f, 0.f, 0.f);
    float4 a1 = a0, a2 = a0, a3 = a0;
    float dpart = 0.f;

    unsigned ro = (unsigned)((esub < cnt) ? sidx[wv][esub] : 0) * 16 + (dsub << 1);
    uint4 g0 = kb4[ro];
    uint4 g1 = kb4[ro + 1];

    for (int i0 = 0; i0 < cnt; i0 += 8) {
        int inx = i0 + 8 + esub;
        unsigned rn = (unsigned)((inx < cnt) ? sidx[wv][inx] : 0) * 16 + (dsub << 1);
        uint4 n0 = kb4[rn];
        uint4 n1 = kb4[rn + 1];
        int i = i0 + esub;
        float f0, f1, f2, f3, f4, f5, f6, f7;
        float f8, f9, f10, f11, f12, f13, f14, f15;
        UPK2(g0.x, f0, f1);   UPK2(g0.y, f2, f3);
        UPK2(g0.z, f4, f5);   UPK2(g0.w, f6, f7);
        UPK2(g1.x, f8, f9);   UPK2(g1.y, f10, f11);
        UPK2(g1.z, f12, f13); UPK2(g1.w, f14, f15);
        float dA = 0.f, dB = 0.f;
        dA = fmaf(f0, qr0.x, dA);  dB = fmaf(f1, qr0.y, dB);
        dA = fmaf(f2, qr0.z, dA);  dB = fmaf(f3, qr0.w, dB);
        dA = fmaf(f4, qr1.x, dA);  dB = fmaf(f5, qr1.y, dB);
        dA = fmaf(f6, qr1.z, dA);  dB = fmaf(f7, qr1.w, dB);
        dA = fmaf(f8, qr2.x, dA);  dB = fmaf(f9, qr2.y, dB);
        dA = fmaf(f10, qr2.z, dA); dB = fmaf(f11, qr2.w, dB);
        dA = fmaf(f12, qr3.x, dA); dB = fmaf(f13, qr3.y, dB);
        dA = fmaf(f14, qr3.z, dA); dB = fmaf(f15, qr3.w, dB);
        float d = dA + dB;
        d += __shfl_xor(d, 1);
        d += __shfl_xor(d, 2);
        d += __shfl_xor(d, 4);           // all 8 lanes of entry hold full dot
        float p = d + wb;
        p = p >= 0.f ? p : 0.2f * p;     // LeakyReLU(0.2), commutes with log2e scale
        float ww = (i < cnt) ? exp2f(p) : 0.f;
        dpart += ww;
        a0.x = fmaf(ww, f0, a0.x);  a0.y = fmaf(ww, f1, a0.y);
        a0.z = fmaf(ww, f2, a0.z);  a0.w = fmaf(ww, f3, a0.w);
        a1.x = fmaf(ww, f4, a1.x);  a1.y = fmaf(ww, f5, a1.y);
        a1.z = fmaf(ww, f6, a1.z);  a1.w = fmaf(ww, f7, a1.w);
        a2.x = fmaf(ww, f8, a2.x);  a2.y = fmaf(ww, f9, a2.y);
        a2.z = fmaf(ww, f10, a2.z); a2.w = fmaf(ww, f11, a2.w);
        a3.x = fmaf(ww, f12, a3.x); a3.y = fmaf(ww, f13, a3.y);
        a3.z = fmaf(ww, f14, a3.z); a3.w = fmaf(ww, f15, a3.w);
        g0 = n0; g1 = n1;
    }

#define RED3(f) f += __shfl_xor(f, 8); f += __shfl_xor(f, 16); f += __shfl_xor(f, 32)
    RED3(a0.x); RED3(a0.y); RED3(a0.z); RED3(a0.w);
    RED3(a1.x); RED3(a1.y); RED3(a1.z); RED3(a1.w);
    RED3(a2.x); RED3(a2.y); RED3(a2.z); RED3(a2.w);
    RED3(a3.x); RED3(a3.y); RED3(a3.z); RED3(a3.w);
#undef RED3
    float denom = wave_sum64(dpart) * 0.125f;   // each entry counted by 8 lanes
    float rden = denom > 0.f ? 1.0f / denom : 0.f;

    if (esub == 0) {                      // lanes 0..7, lane == dsub
        a0.x *= rden; a0.y *= rden; a0.z *= rden; a0.w *= rden;
        a1.x *= rden; a1.y *= rden; a1.z *= rden; a1.w *= rden;
        a2.x *= rden; a2.y *= rden; a2.z *= rden; a2.w *= rden;
        a3.x *= rden; a3.y *= rden; a3.z *= rden; a3.w *= rden;
        float4* op = (float4*)out + (size_t)br * 32 + (dsub << 2);
        op[0] = a0; op[1] = a1; op[2] = a2; op[3] = a3;
        if (wbf) {
            ushort4* hp = (ushort4*)out_bf + (size_t)br * 32 + (dsub << 2);
            ushort4 h0, h1, h2, h3;
            h0.x = f2bf(a0.x); h0.y = f2bf(a0.y); h0.z = f2bf(a0.z); h0.w = f2bf(a0.w);
            h1.x = f2bf(a1.x); h1.y = f2bf(a1.y); h1.z = f2bf(a1.z); h1.w = f2bf(a1.w);
            h2.x = f2bf(a2.x); h2.y = f2bf(a2.y); h2.z = f2bf(a2.z); h2.w = f2bf(a2.w);
            h3.x = f2bf(a3.x); h3.y = f2bf(a3.y); h3.z = f2bf(a3.z); h3.w = f2bf(a3.w);
            hp[0] = h0; hp[1] = h1; hp[2] = h2; hp[3] = h3;
        }
    }
}

extern "C" void kernel_launch(void* const* d_in, const int* in_sizes, int n_in,
                              void* d_out, int out_size, void* d_ws, size_t ws_size,
                              hipStream_t stream) {
    const float* nodes_in = (const float*)d_in[0];   // (B,N,H) f32
    const float* adj      = (const float*)d_in[1];   // (B,E,N) f32, binary
    const float* w1       = (const float*)d_in[2];   // (H+1)
    const float* w2       = (const float*)d_in[3];   // (H+1)

    char* ws = (char*)d_ws;
    size_t off = 0;
    u16* row_idx = (u16*)(ws + off); off += (size_t)B_ * E_ * CAP * sizeof(u16);
    u16* col_idx = (u16*)(ws + off); off += (size_t)B_ * N_ * CAP * sizeof(u16);
    int* row_cnt = (int*)(ws + off); off += (size_t)B_ * E_ * sizeof(int);
    int* col_cnt = (int*)(ws + off); off += (size_t)B_ * N_ * sizeof(int);
    int* cnt_chunk = (int*)(ws + off); off += (size_t)B_ * NC * N_ * sizeof(int);
    int* off_chunk = (int*)(ws + off); off += (size_t)B_ * NC * N_ * sizeof(int);
    u16* nodes_bf = (u16*)(ws + off); off += (size_t)B_ * N_ * H_ * sizeof(u16);
    u16* edge_bf  = (u16*)(ws + off); off += (size_t)B_ * E_ * H_ * sizeof(u16);

    float* out_nodes = (float*)d_out;                       // (B,N,H)
    float* out_edge  = out_nodes + (size_t)B_ * N_ * H_;    // (B,E,H)

    build_rows<<<dim3(B_ * E_), dim3(256), 0, stream>>>(adj, row_idx, row_cnt);
    col_count <<<dim3(B_ * NC * 4), dim3(256), 0, stream>>>(adj, cnt_chunk);
    col_prefix<<<dim3(B_ * N_ / 256), dim3(256), 0, stream>>>(cnt_chunk, off_chunk, col_cnt);
    col_place <<<dim3(B_ * NC * 4), dim3(256), 0, stream>>>(adj, off_chunk, col_idx);
    to_bf16   <<<dim3(B_ * N_ * H_ / 1024), dim3(256), 0, stream>>>(nodes_in, nodes_bf);
    edge_init <<<dim3(B_ * E_ / 4), dim3(256), 0, stream>>>(nodes_bf, row_idx, row_cnt, out_edge);

    const float* ncur = nodes_in;
    for (int s = 0; s < 2; ++s) {
        // edge = alpha(edge_q, nodes_kv); writes fp32 out_edge + bf16 edge_bf
        attn_gather<<<dim3(B_ * E_ / 4), dim3(256), 0, stream>>>(
            out_edge, nodes_bf, w1, row_idx, row_cnt, out_edge, edge_bf, 1);
        // nodes = beta(nodes_q, edge_kv); writes fp32 out_nodes (+ bf16 unless last)
        attn_gather<<<dim3(B_ * N_ / 4), dim3(256), 0, stream>>>(
            ncur, edge_bf, w2, col_idx, col_cnt, out_nodes, nodes_bf, s == 0 ? 1 : 0);
        ncur = out_nodes;
    }
}

// Round 12
// 232.547 us; speedup vs baseline: 1.5076x; 1.0010x over previous
//
#include <hip/hip_runtime.h>
#include <cstdint>
#include <cstddef>

#define B_ 16
#define E_ 1024
#define N_ 1024
#define H_ 128
#define CAP 192   // max nonzeros per row/col; Binomial(1024,0.1): mean 102, std 9.6 -> 192 = 9.3 sigma
#define NC 32     // e-chunks for column build
#define EC 32     // E_/NC
#define NW 16     // u64 words per 1024-bit row

typedef unsigned short u16;
typedef unsigned long long u64;

#define UPK2(u, flo, fhi) \
    flo = __uint_as_float((u) << 16); fhi = __uint_as_float((u) & 0xffff0000u)

__device__ __forceinline__ u16 f2bf(float f) {   // RTNE float->bf16
    unsigned u = __float_as_uint(f);
    return (u16)((u + 0x7fffu + ((u >> 16) & 1u)) >> 16);
}

__device__ __forceinline__ float wave_sum64(float v) {
    v += __shfl_xor(v, 32);
    v += __shfl_xor(v, 16);
    v += __shfl_xor(v, 8);
    v += __shfl_xor(v, 4);
    v += __shfl_xor(v, 2);
    v += __shfl_xor(v, 1);
    return v;
}

// --- adj (B,E,N) f32 -> bit matrix (B*E rows x 16 u64 words), single pass ---
__global__ void adj_to_bits(const float* __restrict__ adj, u64* __restrict__ bits) {
    int be = blockIdx.x;                      // 16384
    const float* row = adj + (size_t)be * N_;
    int tid = threadIdx.x, lane = tid & 63, wv = tid >> 6;
    for (int c0 = 0; c0 < N_; c0 += 256) {
        float v = row[c0 + tid];
        u64 m = __ballot(v != 0.0f);
        if (lane == 0) bits[(size_t)be * NW + (c0 >> 6) + wv] = m;
    }
}

// --- Row lists from bits: wave per row, 4 rows/block. Ascending n. ---
__global__ void rows_from_bits(const u64* __restrict__ bits,
                               u16* __restrict__ idx, int* __restrict__ cnt_out) {
    int x = blockIdx.x;                       // 4096
    int tid = threadIdx.x, lane = tid & 63, wv = tid >> 6;
    int be = (x << 2) + wv;
    const u64* wds = bits + (size_t)be * NW;
    u64 m = (lane < NW) ? wds[lane] : 0ull;
    int pc = __popcll(m);
    int inc = pc;
#pragma unroll
    for (int o = 1; o < 64; o <<= 1) {
        int t = __shfl_up(inc, o);
        if (lane >= o) inc += t;
    }
    int excl = inc - pc;
    int total = __shfl(inc, 63);
    u16* lst = idx + (size_t)be * CAP;
    int pos = excl;
    u64 mm = m;
    while (mm) {
        int bno = __ffsll(mm) - 1;
        if (pos < CAP) lst[pos] = (u16)((lane << 6) + bno);
        ++pos;
        mm &= mm - 1;
    }
    if (lane == 0) cnt_out[be] = total < CAP ? total : CAP;
}

// --- Column lists from bits, 3-phase (ascending e), broadcast word reads ---
__global__ void col_count_bits(const u64* __restrict__ bits, int* __restrict__ cnt_chunk) {
    int blk = blockIdx.x;                 // B*NC*4 = 2048
    int ng = blk & 3;
    int c  = (blk >> 2) & (NC - 1);
    int b  = blk >> 7;
    int n = (ng << 8) + threadIdx.x;
    const u64* base = bits + ((size_t)(b * E_ + c * EC)) * NW + (n >> 6);
    u64 sel = 1ull << (n & 63);
    int cc = 0;
#pragma unroll 8
    for (int e = 0; e < EC; ++e)
        cc += (base[(size_t)e * NW] & sel) ? 1 : 0;
    cnt_chunk[(size_t)(b * NC + c) * N_ + n] = cc;
}

__global__ void col_prefix(const int* __restrict__ cnt_chunk,
                           int* __restrict__ off_chunk, int* __restrict__ cnt_out) {
    int idx = blockIdx.x * 256 + threadIdx.x;   // b*N + n
    int b = idx >> 10, n = idx & 1023;
    int run = 0;
    for (int c = 0; c < NC; ++c) {
        size_t p = (size_t)(b * NC + c) * N_ + n;
        off_chunk[p] = run;
        run += cnt_chunk[p];
    }
    cnt_out[idx] = run < CAP ? run : CAP;
}

__global__ void col_place_bits(const u64* __restrict__ bits,
                               const int* __restrict__ off_chunk, u16* __restrict__ idx) {
    int blk = blockIdx.x;                 // 2048
    int ng = blk & 3;
    int c  = (blk >> 2) & (NC - 1);
    int b  = blk >> 7;
    int n = (ng << 8) + threadIdx.x;
    const u64* base = bits + ((size_t)(b * E_ + c * EC)) * NW + (n >> 6);
    u64 sel = 1ull << (n & 63);
    int pos = off_chunk[(size_t)(b * NC + c) * N_ + n];
    u16* lst = idx + ((size_t)b * N_ + n) * CAP;
    for (int e = 0; e < EC; ++e) {
        if (base[(size_t)e * NW] & sel) {
            if (pos < CAP) lst[pos] = (u16)(c * EC + e);
            ++pos;
        }
    }
}

// One-time fp32 -> bf16 copy (nodes). 4 elems/thread.
__global__ void to_bf16(const float* __restrict__ in, u16* __restrict__ out) {
    int i = blockIdx.x * 256 + threadIdx.x;     // float4 index
    float4 v = ((const float4*)in)[i];
    ushort4 r;
    r.x = f2bf(v.x); r.y = f2bf(v.y); r.z = f2bf(v.z); r.w = f2bf(v.w);
    ((ushort4*)out)[i] = r;
}

// Wave-per-row edge_init: edge[b,e,:] = mean of incident bf16 node rows.
__global__ void __launch_bounds__(256, 8)
edge_init(const u16* __restrict__ nodes_bf,
          const u16* __restrict__ ridx, const int* __restrict__ rcnt,
          float* __restrict__ edge) {
    int x = blockIdx.x;                  // B_*E_/4 = 4096
    int xcd = x & 7;
    int j = x >> 3;                      // 0..511
    int b = xcd + ((j >> 8) << 3);       // batches {xcd, xcd+8}
    int rg = (j & 255) << 2;
    int tid = threadIdx.x, lane = tid & 63, wv = tid >> 6;
    int be = (b << 10) + rg + wv;        // this wave's edge row
    __shared__ u16 sidx[4][CAP];
    int cnt = rcnt[be];
    for (int i = lane; i < cnt; i += 64) sidx[wv][i] = ridx[(size_t)be * CAP + i];

    int esub = lane >> 3, dsub = lane & 7;
    const uint4* kb4 = (const uint4*)(nodes_bf + (size_t)b * N_ * H_);
    float4 a0 = make_float4(0.f, 0.f, 0.f, 0.f);
    float4 a1 = a0, a2 = a0, a3 = a0;

    unsigned ro = (unsigned)((esub < cnt) ? sidx[wv][esub] : 0) * 16 + (dsub << 1);
    uint4 g0 = kb4[ro];
    uint4 g1 = kb4[ro + 1];

    for (int i0 = 0; i0 < cnt; i0 += 8) {
        int inx = i0 + 8 + esub;
        unsigned rn = (unsigned)((inx < cnt) ? sidx[wv][inx] : 0) * 16 + (dsub << 1);
        uint4 n0 = kb4[rn];
        uint4 n1 = kb4[rn + 1];
        int i = i0 + esub;
        float f0, f1, f2, f3, f4, f5, f6, f7;
        float f8, f9, f10, f11, f12, f13, f14, f15;
        UPK2(g0.x, f0, f1);   UPK2(g0.y, f2, f3);
        UPK2(g0.z, f4, f5);   UPK2(g0.w, f6, f7);
        UPK2(g1.x, f8, f9);   UPK2(g1.y, f10, f11);
        UPK2(g1.z, f12, f13); UPK2(g1.w, f14, f15);
        float ww = (i < cnt) ? 1.0f : 0.f;
        a0.x = fmaf(ww, f0, a0.x);  a0.y = fmaf(ww, f1, a0.y);
        a0.z = fmaf(ww, f2, a0.z);  a0.w = fmaf(ww, f3, a0.w);
        a1.x = fmaf(ww, f4, a1.x);  a1.y = fmaf(ww, f5, a1.y);
        a1.z = fmaf(ww, f6, a1.z);  a1.w = fmaf(ww, f7, a1.w);
        a2.x = fmaf(ww, f8, a2.x);  a2.y = fmaf(ww, f9, a2.y);
        a2.z = fmaf(ww, f10, a2.z); a2.w = fmaf(ww, f11, a2.w);
        a3.x = fmaf(ww, f12, a3.x); a3.y = fmaf(ww, f13, a3.y);
        a3.z = fmaf(ww, f14, a3.z); a3.w = fmaf(ww, f15, a3.w);
        g0 = n0; g1 = n1;
    }

#define RED3(f) f += __shfl_xor(f, 8); f += __shfl_xor(f, 16); f += __shfl_xor(f, 32)
    RED3(a0.x); RED3(a0.y); RED3(a0.z); RED3(a0.w);
    RED3(a1.x); RED3(a1.y); RED3(a1.z); RED3(a1.w);
    RED3(a2.x); RED3(a2.y); RED3(a2.z); RED3(a2.w);
    RED3(a3.x); RED3(a3.y); RED3(a3.z); RED3(a3.w);
#undef RED3
    if (esub == 0) {
        float inv = 1.0f / (float)(cnt > 0 ? cnt : 1);
        a0.x *= inv; a0.y *= inv; a0.z *= inv; a0.w *= inv;
        a1.x *= inv; a1.y *= inv; a1.z *= inv; a1.w *= inv;
        a2.x *= inv; a2.y *= inv; a2.z *= inv; a2.w *= inv;
        a3.x *= inv; a3.y *= inv; a3.z *= inv; a3.w *= inv;
        float4* op = (float4*)edge + (size_t)be * 32 + (dsub << 2);
        op[0] = a0; op[1] = a1; op[2] = a2; op[3] = a3;
    }
}

// Wave-per-row fused masked-softmax attention, bf16 KV gather.
// wbf=0 skips the bf16 shadow write (dead in the final beta dispatch).
__global__ void __launch_bounds__(256, 8)
attn_gather(const float* __restrict__ qsrc,
            const u16* __restrict__ kv_bf,
            const float* __restrict__ w,
            const u16* __restrict__ lidx, const int* __restrict__ lcnt,
            float* __restrict__ out, u16* __restrict__ out_bf, int wbf) {
    int x = blockIdx.x;                  // 4096 blocks
    int xcd = x & 7;
    int j = x >> 3;                      // 0..511
    int b = xcd + ((j >> 8) << 3);       // batches {xcd, xcd+8}
    int rg = (j & 255) << 2;             // 4-row group
    int tid = threadIdx.x, lane = tid & 63, wv = tid >> 6;
    int br = (b << 10) + rg + wv;        // this wave's row
    __shared__ u16 sidx[4][CAP];
    int cnt = lcnt[br];
    for (int i = lane; i < cnt; i += 64) sidx[wv][i] = lidx[(size_t)br * CAP + i];

    int esub = lane >> 3, dsub = lane & 7;   // entry-in-round, d-slice
    const float4* qp = (const float4*)(qsrc + (size_t)br * H_);
    const float4* wp = (const float4*)w;
    float4 qr0, qr1, qr2, qr3;
    {
        float4 q0 = qp[(dsub << 2) + 0], w0 = wp[(dsub << 2) + 0];
        float4 q1 = qp[(dsub << 2) + 1], w1 = wp[(dsub << 2) + 1];
        float4 q2 = qp[(dsub << 2) + 2], w2 = wp[(dsub << 2) + 2];
        float4 q3 = qp[(dsub << 2) + 3], w3 = wp[(dsub << 2) + 3];
        const float L2E = 1.44269504f;
        qr0.x = q0.x * w0.x * L2E; qr0.y = q0.y * w0.y * L2E;
        qr0.z = q0.z * w0.z * L2E; qr0.w = q0.w * w0.w * L2E;
        qr1.x = q1.x * w1.x * L2E; qr1.y = q1.y * w1.y * L2E;
        qr1.z = q1.z * w1.z * L2E; qr1.w = q1.w * w1.w * L2E;
        qr2.x = q2.x * w2.x * L2E; qr2.y = q2.y * w2.y * L2E;
        qr2.z = q2.z * w2.z * L2E; qr2.w = q2.w * w2.w * L2E;
        qr3.x = q3.x * w3.x * L2E; qr3.y = q3.y * w3.y * L2E;
        qr3.z = q3.z * w3.z * L2E; qr3.w = q3.w * w3.w * L2E;
    }
    float wb = w[H_] * 1.44269504f;
    const uint4* kb4 = (const uint4*)(kv_bf + (size_t)b * 1024 * H_);

    float4 a0 = make_float4(0.f, 0.f, 0.f, 0.f);
    float4 a1 = a0, a2 = a0, a3 = a0;
    float dpart = 0.f;

    unsigned ro = (unsigned)((esub < cnt) ? sidx[wv][esub] : 0) * 16 + (dsub << 1);
    uint4 g0 = kb4[ro];
    uint4 g1 = kb4[ro + 1];

    for (int i0 = 0; i0 < cnt; i0 += 8) {
        int inx = i0 + 8 + esub;
        unsigned rn = (unsigned)((inx < cnt) ? sidx[wv][inx] : 0) * 16 + (dsub << 1);
        uint4 n0 = kb4[rn];
        uint4 n1 = kb4[rn + 1];
        int i = i0 + esub;
        float f0, f1, f2, f3, f4, f5, f6, f7;
        float f8, f9, f10, f11, f12, f13, f14, f15;
        UPK2(g0.x, f0, f1);   UPK2(g0.y, f2, f3);
        UPK2(g0.z, f4, f5);   UPK2(g0.w, f6, f7);
        UPK2(g1.x, f8, f9);   UPK2(g1.y, f10, f11);
        UPK2(g1.z, f12, f13); UPK2(g1.w, f14, f15);
        float dA = 0.f, dB = 0.f;
        dA = fmaf(f0, qr0.x, dA);  dB = fmaf(f1, qr0.y, dB);
        dA = fmaf(f2, qr0.z, dA);  dB = fmaf(f3, qr0.w, dB);
        dA = fmaf(f4, qr1.x, dA);  dB = fmaf(f5, qr1.y, dB);
        dA = fmaf(f6, qr1.z, dA);  dB = fmaf(f7, qr1.w, dB);
        dA = fmaf(f8, qr2.x, dA);  dB = fmaf(f9, qr2.y, dB);
        dA = fmaf(f10, qr2.z, dA); dB = fmaf(f11, qr2.w, dB);
        dA = fmaf(f12, qr3.x, dA); dB = fmaf(f13, qr3.y, dB);
        dA = fmaf(f14, qr3.z, dA); dB = fmaf(f15, qr3.w, dB);
        float d = dA + dB;
        d += __shfl_xor(d, 1);
        d += __shfl_xor(d, 2);
        d += __shfl_xor(d, 4);           // all 8 lanes of entry hold full dot
        float p = d + wb;
        p = p >= 0.f ? p : 0.2f * p;     // LeakyReLU(0.2), commutes with log2e scale
        float ww = (i < cnt) ? exp2f(p) : 0.f;
        dpart += ww;
        a0.x = fmaf(ww, f0, a0.x);  a0.y = fmaf(ww, f1, a0.y);
        a0.z = fmaf(ww, f2, a0.z);  a0.w = fmaf(ww, f3, a0.w);
        a1.x = fmaf(ww, f4, a1.x);  a1.y = fmaf(ww, f5, a1.y);
        a1.z = fmaf(ww, f6, a1.z);  a1.w = fmaf(ww, f7, a1.w);
        a2.x = fmaf(ww, f8, a2.x);  a2.y = fmaf(ww, f9, a2.y);
        a2.z = fmaf(ww, f10, a2.z); a2.w = fmaf(ww, f11, a2.w);
        a3.x = fmaf(ww, f12, a3.x); a3.y = fmaf(ww, f13, a3.y);
        a3.z = fmaf(ww, f14, a3.z); a3.w = fmaf(ww, f15, a3.w);
        g0 = n0; g1 = n1;
    }

#define RED3(f) f += __shfl_xor(f, 8); f += __shfl_xor(f, 16); f += __shfl_xor(f, 32)
    RED3(a0.x); RED3(a0.y); RED3(a0.z); RED3(a0.w);
    RED3(a1.x); RED3(a1.y); RED3(a1.z); RED3(a1.w);
    RED3(a2.x); RED3(a2.y); RED3(a2.z); RED3(a2.w);
    RED3(a3.x); RED3(a3.y); RED3(a3.z); RED3(a3.w);
#undef RED3
    float denom = wave_sum64(dpart) * 0.125f;   // each entry counted by 8 lanes
    float rden = denom > 0.f ? 1.0f / denom : 0.f;

    if (esub == 0) {                      // lanes 0..7, lane == dsub
        a0.x *= rden; a0.y *= rden; a0.z *= rden; a0.w *= rden;
        a1.x *= rden; a1.y *= rden; a1.z *= rden; a1.w *= rden;
        a2.x *= rden; a2.y *= rden; a2.z *= rden; a2.w *= rden;
        a3.x *= rden; a3.y *= rden; a3.z *= rden; a3.w *= rden;
        float4* op = (float4*)out + (size_t)br * 32 + (dsub << 2);
        op[0] = a0; op[1] = a1; op[2] = a2; op[3] = a3;
        if (wbf) {
            ushort4* hp = (ushort4*)out_bf + (size_t)br * 32 + (dsub << 2);
            ushort4 h0, h1, h2, h3;
            h0.x = f2bf(a0.x); h0.y = f2bf(a0.y); h0.z = f2bf(a0.z); h0.w = f2bf(a0.w);
            h1.x = f2bf(a1.x); h1.y = f2bf(a1.y); h1.z = f2bf(a1.z); h1.w = f2bf(a1.w);
            h2.x = f2bf(a2.x); h2.y = f2bf(a2.y); h2.z = f2bf(a2.z); h2.w = f2bf(a2.w);
            h3.x = f2bf(a3.x); h3.y = f2bf(a3.y); h3.z = f2bf(a3.z); h3.w = f2bf(a3.w);
            hp[0] = h0; hp[1] = h1; hp[2] = h2; hp[3] = h3;
        }
    }
}

extern "C" void kernel_launch(void* const* d_in, const int* in_sizes, int n_in,
                              void* d_out, int out_size, void* d_ws, size_t ws_size,
                              hipStream_t stream) {
    const float* nodes_in = (const float*)d_in[0];   // (B,N,H) f32
    const float* adj      = (const float*)d_in[1];   // (B,E,N) f32, binary
    const float* w1       = (const float*)d_in[2];   // (H+1)
    const float* w2       = (const float*)d_in[3];   // (H+1)

    char* ws = (char*)d_ws;
    size_t off = 0;
    u16* row_idx = (u16*)(ws + off); off += (size_t)B_ * E_ * CAP * sizeof(u16);
    u16* col_idx = (u16*)(ws + off); off += (size_t)B_ * N_ * CAP * sizeof(u16);
    int* row_cnt = (int*)(ws + off); off += (size_t)B_ * E_ * sizeof(int);
    int* col_cnt = (int*)(ws + off); off += (size_t)B_ * N_ * sizeof(int);
    int* cnt_chunk = (int*)(ws + off); off += (size_t)B_ * NC * N_ * sizeof(int);
    int* off_chunk = (int*)(ws + off); off += (size_t)B_ * NC * N_ * sizeof(int);
    u16* nodes_bf = (u16*)(ws + off); off += (size_t)B_ * N_ * H_ * sizeof(u16);
    u16* edge_bf  = (u16*)(ws + off); off += (size_t)B_ * E_ * H_ * sizeof(u16);
    u64* bits     = (u64*)(ws + off); off += (size_t)B_ * E_ * NW * sizeof(u64);

    float* out_nodes = (float*)d_out;                       // (B,N,H)
    float* out_edge  = out_nodes + (size_t)B_ * N_ * H_;    // (B,E,H)

    adj_to_bits   <<<dim3(B_ * E_), dim3(256), 0, stream>>>(adj, bits);
    rows_from_bits<<<dim3(B_ * E_ / 4), dim3(256), 0, stream>>>(bits, row_idx, row_cnt);
    col_count_bits<<<dim3(B_ * NC * 4), dim3(256), 0, stream>>>(bits, cnt_chunk);
    col_prefix    <<<dim3(B_ * N_ / 256), dim3(256), 0, stream>>>(cnt_chunk, off_chunk, col_cnt);
    col_place_bits<<<dim3(B_ * NC * 4), dim3(256), 0, stream>>>(bits, off_chunk, col_idx);
    to_bf16       <<<dim3(B_ * N_ * H_ / 1024), dim3(256), 0, stream>>>(nodes_in, nodes_bf);
    edge_init     <<<dim3(B_ * E_ / 4), dim3(256), 0, stream>>>(nodes_bf, row_idx, row_cnt, out_edge);

    const float* ncur = nodes_in;
    for (int s = 0; s < 2; ++s) {
        // edge = alpha(edge_q, nodes_kv); writes fp32 out_edge + bf16 edge_bf
        attn_gather<<<dim3(B_ * E_ / 4), dim3(256), 0, stream>>>(
            out_edge, nodes_bf, w1, row_idx, row_cnt, out_edge, edge_bf, 1);
        // nodes = beta(nodes_q, edge_kv); writes fp32 out_nodes (+ bf16 unless last)
        attn_gather<<<dim3(B_ * N_ / 4), dim3(256), 0, stream>>>(
            ncur, edge_bf, w2, col_idx, col_cnt, out_nodes, nodes_bf, s == 0 ? 1 : 0);
        ncur = out_nodes;
    }
}